// Round 7
// baseline (325.804 us; speedup 1.0000x reference)
//
#include <hip/hip_runtime.h>
#include <math.h>

#define NATOMS 4096
#define FDIM   256
#define NHEAD  8
#define DHEAD  32
#define NGRP   128

// grid layout
#define NB_QKV   512
#define NB_A2    64
#define B_OFF    (NB_QKV + NB_A2)          // 576
#define B_ATTN0  (B_OFF + 1)               // 577
#define NB_ATTN  256                       // 4 (g,h) jobs each
#define B_TAIL0  (B_ATTN0 + NB_ATTN)       // 833
#define NB_TAIL  64
#define NB_ALL   (B_TAIL0 + NB_TAIL)       // 897

// flag indices (64B apart)
#define F_READY  0
#define F_QKV    16
#define F_A2     32
#define F_ATTN   48

typedef __bf16 bf16x8 __attribute__((ext_vector_type(8)));
typedef float  floatx4 __attribute__((ext_vector_type(4)));

__device__ __forceinline__ float silu_f(float x) {
    return x / (1.0f + __expf(-x));
}

__device__ __forceinline__ bf16x8 cvt8(const float* __restrict__ p) {
    float4 f0 = *(const float4*)p;
    float4 f1 = *(const float4*)(p + 4);
    bf16x8 r;
    r[0] = (__bf16)f0.x; r[1] = (__bf16)f0.y; r[2] = (__bf16)f0.z; r[3] = (__bf16)f0.w;
    r[4] = (__bf16)f1.x; r[5] = (__bf16)f1.y; r[6] = (__bf16)f1.z; r[7] = (__bf16)f1.w;
    return r;
}

__device__ __forceinline__ void wait_eq(int* p, int val) {
    while (__hip_atomic_load(p, __ATOMIC_ACQUIRE, __HIP_MEMORY_SCOPE_AGENT) != val)
        __builtin_amdgcn_s_sleep(2);
}

__device__ __forceinline__ void signal_add(int* p) {
    __hip_atomic_fetch_add(p, 1, __ATOMIC_RELEASE, __HIP_MEMORY_SCOPE_AGENT);
}

// LDS: union across phases, 16 KB max -> >=4 blocks/CU with VGPR<=128.
struct SM {
    union {
        struct {                               // attention (~14.5 KB)
            float4 qt4[64 * 8];
            float4 vt4[32 * 8];
            float  wred[8][32];
            float  w[32];
            float  red[8][32];
        } a;
        int segs[NATOMS];                      // offsets phase (16 KB)
        struct { float As[32][33]; float Bs[32][33]; } g;   // A2 gemm
        struct { float As[32][17]; float Bs[32][33]; } t;   // tail gemm
    };
};

// ---------------------------------------------------------------------------
// Single fused kernel: all phases gated by device-scope counters.
// Co-residency guaranteed (897 blocks <= 4 blocks/CU * 256 CU), so the
// point-to-point spins cannot deadlock under any dispatch order.
// ---------------------------------------------------------------------------
__global__ __launch_bounds__(256, 4) void fused_all(
    const float* __restrict__ x, const int* __restrict__ seg,
    const float* __restrict__ Wq, const float* __restrict__ Wk, const float* __restrict__ Wv,
    const float* __restrict__ bq, const float* __restrict__ bk, const float* __restrict__ bv,
    const float* __restrict__ Wo1, const float* __restrict__ bo1,
    const float* __restrict__ Wo2, const float* __restrict__ bo2,
    float* __restrict__ out,
    float* __restrict__ qkv, float* __restrict__ Ysum,
    float* __restrict__ A2, float* __restrict__ c1,
    float* __restrict__ cntf, int* __restrict__ off, int* __restrict__ flags)
{
    __shared__ SM sm;
    const int tid = threadIdx.x;
    const int bid = blockIdx.x;

    if (bid < NB_QKV) {
        // ============ QKV projection tile via bf16 MFMA (inline cvt) ============
        int lane = tid & 63;
        int ww = tid >> 6;
        int wrow = ww >> 1, wcol = ww & 1;
        int tm = bid & 63;
        int tn = bid >> 6;                 // 0..7
        int m_base = tm * 64 + wrow * 32;
        int n_base = tn * 96 + wcol * 48;

        int l15 = lane & 15;
        int quad = lane >> 4;
        int kq = quad * 8;

        floatx4 acc[2][3] = {};

        const float* arow0 = x + (size_t)(m_base + l15) * 256 + kq;
        const float* arow1 = arow0 + 16 * 256;
        const float* brow[3];
        const float* bias[3];
#pragma unroll
        for (int ni = 0; ni < 3; ++ni) {
            int col = n_base + ni * 16 + l15;
            int w = col >> 8, c = col & 255;
            const float* W = (w == 0) ? Wq : (w == 1) ? Wk : Wv;
            brow[ni] = W + (size_t)c * 256 + kq;
            bias[ni] = ((w == 0) ? bq : (w == 1) ? bk : bv) + c;
        }

#pragma unroll
        for (int ks = 0; ks < 8; ++ks) {
            int ko = ks * 32;
            bf16x8 a0 = cvt8(arow0 + ko);
            bf16x8 a1 = cvt8(arow1 + ko);
#pragma unroll
            for (int ni = 0; ni < 3; ++ni) {
                bf16x8 b = cvt8(brow[ni] + ko);
                acc[0][ni] = __builtin_amdgcn_mfma_f32_16x16x32_bf16(a0, b, acc[0][ni], 0, 0, 0);
                acc[1][ni] = __builtin_amdgcn_mfma_f32_16x16x32_bf16(a1, b, acc[1][ni], 0, 0, 0);
            }
        }

#pragma unroll
        for (int mi = 0; mi < 2; ++mi) {
#pragma unroll
            for (int ni = 0; ni < 3; ++ni) {
                int col = n_base + ni * 16 + l15;
                int w = col >> 8, c = col & 255;
                float bb = *bias[ni];
                float* outp = qkv + (size_t)w * ((size_t)NATOMS * FDIM) + c;
#pragma unroll
                for (int r = 0; r < 4; ++r) {
                    int row = m_base + mi * 16 + quad * 4 + r;
                    outp[(size_t)row * FDIM] = acc[mi][ni][r] + bb;
                }
            }
        }
        __threadfence();
        __syncthreads();
        if (tid == 0) { wait_eq(&flags[F_READY], 1); signal_add(&flags[F_QKV]); }

    } else if (bid < B_OFF) {
        // ====== A2 = Wo2 @ Wo1 (fp32 NN, 32x32); j0==0 blocks also fold c1 ======
        int t = bid - NB_QKV;
        int i0 = (t >> 3) * 32;
        int j0 = (t & 7) * 32;
        bool do_c1 = (t & 7) == 0;
        int tx = tid & 15;
        int ty = tid >> 4;
        int lm = tid >> 3;
        int lk = (tid & 7) << 2;

        float acc[2][2] = {};
        float c1acc = 0.0f;

        for (int kt = 0; kt < 256; kt += 32) {
            const float4 av = *(const float4*)(Wo2 + (size_t)(i0 + lm) * 256 + kt + lk);
            const float4 bv = *(const float4*)(Wo1 + (size_t)(kt + lm) * 256 + j0 + lk);
            sm.g.As[lk + 0][lm] = av.x; sm.g.As[lk + 1][lm] = av.y;
            sm.g.As[lk + 2][lm] = av.z; sm.g.As[lk + 3][lm] = av.w;
            sm.g.Bs[lm][lk + 0] = bv.x; sm.g.Bs[lm][lk + 1] = bv.y;
            sm.g.Bs[lm][lk + 2] = bv.z; sm.g.Bs[lm][lk + 3] = bv.w;
            __syncthreads();

#pragma unroll
            for (int kk = 0; kk < 32; ++kk) {
                float a0 = sm.g.As[kk][ty * 2], a1 = sm.g.As[kk][ty * 2 + 1];
                float b0 = sm.g.Bs[kk][tx * 2], b1 = sm.g.Bs[kk][tx * 2 + 1];
                acc[0][0] = fmaf(a0, b0, acc[0][0]);
                acc[0][1] = fmaf(a0, b1, acc[0][1]);
                acc[1][0] = fmaf(a1, b0, acc[1][0]);
                acc[1][1] = fmaf(a1, b1, acc[1][1]);
            }
            if (do_c1) {
                float4 bb = *(const float4*)(bo1 + kt + lk);
                c1acc = fmaf(sm.g.As[lk + 0][lm], bb.x, c1acc);
                c1acc = fmaf(sm.g.As[lk + 1][lm], bb.y, c1acc);
                c1acc = fmaf(sm.g.As[lk + 2][lm], bb.z, c1acc);
                c1acc = fmaf(sm.g.As[lk + 3][lm], bb.w, c1acc);
            }
            __syncthreads();
        }

#pragma unroll
        for (int i = 0; i < 2; ++i)
#pragma unroll
            for (int j = 0; j < 2; ++j)
                A2[(size_t)(i0 + ty * 2 + i) * 256 + j0 + tx * 2 + j] = acc[i][j];

        if (do_c1) {
            c1acc += __shfl_xor(c1acc, 1, 8);
            c1acc += __shfl_xor(c1acc, 2, 8);
            c1acc += __shfl_xor(c1acc, 4, 8);
            if ((tid & 7) == 0) c1[i0 + lm] = c1acc;
        }
        __threadfence();
        __syncthreads();
        if (tid == 0) { wait_eq(&flags[F_READY], 1); signal_add(&flags[F_A2]); }

    } else if (bid == B_OFF) {
        // ============ counters init + group offsets (LDS-staged seg) ============
        if (tid == 1) flags[F_QKV] = 0;
        if (tid == 2) flags[F_A2] = 0;
        if (tid == 3) flags[F_ATTN] = 0;
        for (int i = tid; i < NATOMS; i += 256) sm.segs[i] = seg[i];
        __syncthreads();
        if (tid < NGRP) {
            int g = tid;
            auto lb = [&](int val) {
                int lo = 0, hi = NATOMS;
                while (lo < hi) {
                    int mid = (lo + hi) >> 1;
                    if (sm.segs[mid] < val) lo = mid + 1; else hi = mid;
                }
                return lo;
            };
            int a = lb(g);
            int b = lb(g + 1);
            off[g] = a;
            if (g == NGRP - 1) off[NGRP] = NATOMS;
            cntf[g] = (float)(b - a);
        }
        __threadfence();
        __syncthreads();
        if (tid == 0)
            __hip_atomic_store(&flags[F_READY], 1, __ATOMIC_RELEASE, __HIP_MEMORY_SCOPE_AGENT);

    } else if (bid < B_TAIL0) {
        // ================= attention: 4 (g,h) jobs per block ====================
        if (tid == 0) wait_eq(&flags[F_QKV], NB_QKV);
        __syncthreads();

        const float* q = qkv;
        const float* k = qkv + (size_t)NATOMS * FDIM;
        const float* v = qkv + 2 * (size_t)NATOMS * FDIM;

        int jj = tid & 31;
        int iq = tid >> 5;
        int d = tid & 31;
        int r = tid >> 5;

        for (int t = 0; t < 4; ++t) {
            int job = (bid - B_ATTN0) * 4 + t;    // 0..1023
            int g = job >> 3, h = job & 7;

            int base = off[g];
            int end  = off[g + 1];
            base = min(max(base, 0), NATOMS);
            end  = min(max(end, base), NATOMS);
            int n = end - base;

            const float4* q4 = (const float4*)(q + (size_t)base * FDIM) + h * 8;
            const float4* k4 = (const float4*)(k + (size_t)base * FDIM) + h * 8;
            const float4* v4 = (const float4*)(v + (size_t)base * FDIM) + h * 8;

            float accY = 0.0f;

            for (int j0 = 0; j0 < n; j0 += 32) {
                int jt_n = min(32, n - j0);
                __syncthreads();
                for (int idx = tid; idx < jt_n * 8; idx += 256)
                    sm.a.vt4[idx] = v4[(size_t)(j0 + (idx >> 3)) * 64 + (idx & 7)];

                float4 kr[8];
                {
                    int jrow = (jj < jt_n) ? (j0 + jj) : j0;
#pragma unroll
                    for (int c = 0; c < 8; ++c) kr[c] = k4[(size_t)jrow * 64 + c];
                }

                float wpart = 0.0f;
                for (int i0 = 0; i0 < n; i0 += 64) {
                    int it_n = min(64, n - i0);
                    __syncthreads();
                    for (int idx = tid; idx < it_n * 8; idx += 256)
                        sm.a.qt4[idx] = q4[(size_t)(i0 + (idx >> 3)) * 64 + (idx & 7)];
                    __syncthreads();
                    if (jj < jt_n) {
                        for (int ii = iq; ii < it_n; ii += 8) {
                            const float4* qr = &sm.a.qt4[ii * 8];
                            float s = 0.0f;
#pragma unroll
                            for (int c = 0; c < 8; ++c) {
                                float4 a = qr[c];
                                s = fmaf(a.x, kr[c].x, s);
                                s = fmaf(a.y, kr[c].y, s);
                                s = fmaf(a.z, kr[c].z, s);
                                s = fmaf(a.w, kr[c].w, s);
                            }
                            wpart += silu_f(s);
                        }
                    }
                }
                sm.a.wred[iq][jj] = wpart;
                __syncthreads();
                if (tid < 32) {
                    float s = 0.0f;
#pragma unroll
                    for (int rr = 0; rr < 8; ++rr) s += sm.a.wred[rr][tid];
                    sm.a.w[tid] = s;
                }
                __syncthreads();
                const float* vts = (const float*)sm.a.vt4;
                for (int j = r; j < jt_n; j += 8)
                    accY = fmaf(sm.a.w[j], vts[j * 32 + d], accY);
            }

            sm.a.red[r][d] = accY;
            __syncthreads();
            if (r == 0) {
                float s = 0.0f;
#pragma unroll
                for (int rr = 0; rr < 8; ++rr) s += sm.a.red[rr][d];
                Ysum[(size_t)g * FDIM + h * DHEAD + d] = s;
            }
            __syncthreads();
        }
        __threadfence();
        __syncthreads();
        if (tid == 0) signal_add(&flags[F_ATTN]);

    } else {
        // ========== tail: out = silu(Ysum @ A2^T + cnt*c1 + bo2) ================
        if (tid == 0) {
            wait_eq(&flags[F_ATTN], NB_ATTN);
            wait_eq(&flags[F_A2], NB_A2);
        }
        __syncthreads();

        int blk = bid - B_TAIL0;
        int bm = (blk >> 3) * 16;
        int bn = (blk & 7) * 32;
        int tx = tid & 15;
        int ty = tid >> 4;

        float acc0 = 0.0f, acc1 = 0.0f;

        for (int kt = 0; kt < 256; kt += 32) {
            if (tid < 128) {
                int row = tid >> 3, kq = (tid & 7) << 2;
                const float4 av = *(const float4*)(Ysum + (size_t)(bm + row) * 256 + kt + kq);
                sm.t.As[kq + 0][row] = av.x; sm.t.As[kq + 1][row] = av.y;
                sm.t.As[kq + 2][row] = av.z; sm.t.As[kq + 3][row] = av.w;
            }
            {
                int row = tid >> 3, kq = (tid & 7) << 2;
                const float4 bv = *(const float4*)(A2 + (size_t)(bn + row) * 256 + kt + kq);
                sm.t.Bs[kq + 0][row] = bv.x; sm.t.Bs[kq + 1][row] = bv.y;
                sm.t.Bs[kq + 2][row] = bv.z; sm.t.Bs[kq + 3][row] = bv.w;
            }
            __syncthreads();

#pragma unroll
            for (int kk = 0; kk < 32; ++kk) {
                float a = sm.t.As[kk][ty];
                acc0 = fmaf(a, sm.t.Bs[kk][tx * 2], acc0);
                acc1 = fmaf(a, sm.t.Bs[kk][tx * 2 + 1], acc1);
            }
            __syncthreads();
        }

        int m = bm + ty;
        float cnt = cntf[m];
        int n0 = bn + tx * 2;
        out[(size_t)m * 256 + n0]     = silu_f(acc0 + cnt * c1[n0] + bo2[n0]);
        out[(size_t)m * 256 + n0 + 1] = silu_f(acc1 + cnt * c1[n0 + 1] + bo2[n0 + 1]);
    }
}

// ---------------------------------------------------------------------------
extern "C" void kernel_launch(void* const* d_in, const int* in_sizes, int n_in,
                              void* d_out, int out_size, void* d_ws, size_t ws_size,
                              hipStream_t stream) {
    const float* x    = (const float*)d_in[0];
    const int*   eidx = (const int*)  d_in[1];
    const float* Wq   = (const float*)d_in[2];
    const float* bq   = (const float*)d_in[3];
    const float* Wk   = (const float*)d_in[4];
    const float* bk   = (const float*)d_in[5];
    const float* Wv   = (const float*)d_in[6];
    const float* bv   = (const float*)d_in[7];
    const float* Wo1  = (const float*)d_in[8];
    const float* bo1  = (const float*)d_in[9];
    const float* Wo2  = (const float*)d_in[10];
    const float* bo2  = (const float*)d_in[11];
    float* out = (float*)d_out;

    const int* seg = eidx + NATOMS;

    const size_t NF = (size_t)NATOMS * FDIM;   // 1,048,576
    const size_t GF = (size_t)NGRP * FDIM;     // 32,768

    float* qkv   = (float*)d_ws;               // q|k|v contiguous, 3*NF
    float* Ysum  = qkv + 3 * NF;               // GF
    float* A2    = Ysum + GF;                  // 256*256
    float* c1    = A2 + 256 * 256;             // 256
    float* cntf  = c1 + 256;                   // 128
    int*   off   = (int*)(cntf + NGRP);        // 160 ints (129 used)
    int*   flags = off + 160;                  // 64 ints (4 used, 64B apart)

    fused_all<<<NB_ALL, 256, 0, stream>>>(x, seg, Wq, Wk, Wv, bq, bk, bv,
                                          Wo1, bo1, Wo2, bo2, out,
                                          qkv, Ysum, A2, c1, cntf, off, flags);
}

// Round 8
// 197.724 us; speedup vs baseline: 1.6478x; 1.6478x over previous
//
#include <hip/hip_runtime.h>
#include <math.h>

#define NATOMS 4096
#define FDIM   256
#define NHEAD  8
#define DHEAD  32
#define NGRP   128

typedef __bf16 bf16x8 __attribute__((ext_vector_type(8)));
typedef float  floatx4 __attribute__((ext_vector_type(4)));

__device__ __forceinline__ float silu_f(float x) {
    return x / (1.0f + __expf(-x));
}

// load 8 consecutive fp32 and convert to a bf16x8 MFMA fragment (RNE)
__device__ __forceinline__ bf16x8 cvt8(const float* __restrict__ p) {
    float4 f0 = *(const float4*)p;
    float4 f1 = *(const float4*)(p + 4);
    bf16x8 r;
    r[0] = (__bf16)f0.x; r[1] = (__bf16)f0.y; r[2] = (__bf16)f0.z; r[3] = (__bf16)f0.w;
    r[4] = (__bf16)f1.x; r[5] = (__bf16)f1.y; r[6] = (__bf16)f1.z; r[7] = (__bf16)f1.w;
    return r;
}

// ---------------------------------------------------------------------------
// K1: 577 blocks.
//  bid <  512 : QKV projection tile via bf16 MFMA, fp32 inputs cvt'd inline.
//               D[4096,768] = x @ [Wq|Wk|Wv]^T + bias -> fp32 q|k|v.
//  512..575   : A2T = (Wo2 @ Wo1)^T  (fp32, 32x32 tiles, stored TRANSPOSED
//               so the fused tail reads coalesced). j0==0 blocks fold
//               c1 = Wo2 @ bo1 out of their LDS-staged Wo2 tile.
//  bid == 576 : group offsets + counts via LDS-staged seg; zeroes gcnt.
// ---------------------------------------------------------------------------
__global__ __launch_bounds__(256) void k1_qkv_a2(
    const float* __restrict__ x, const int* __restrict__ seg,
    const float* __restrict__ Wq, const float* __restrict__ Wk, const float* __restrict__ Wv,
    const float* __restrict__ bq, const float* __restrict__ bk, const float* __restrict__ bv,
    const float* __restrict__ Wo1, const float* __restrict__ bo1,
    const float* __restrict__ Wo2,
    float* __restrict__ qkv, float* __restrict__ A2T, float* __restrict__ c1,
    float* __restrict__ cntf, int* __restrict__ off, int* __restrict__ gcnt)
{
    __shared__ float As[32][33];
    __shared__ float Bs[32][33];
    __shared__ int   segs[NATOMS];

    const int tid = threadIdx.x;
    const int bid = blockIdx.x;

    if (bid < 512) {
        // ---------------- QKV MFMA tile ----------------
        int lane = tid & 63;
        int ww = tid >> 6;
        int wrow = ww >> 1, wcol = ww & 1;
        int tm = bid & 63;
        int tn = bid >> 6;                 // 0..7
        int m_base = tm * 64 + wrow * 32;
        int n_base = tn * 96 + wcol * 48;

        int l15 = lane & 15;
        int quad = lane >> 4;
        int kq = quad * 8;

        floatx4 acc[2][3] = {};

        const float* arow0 = x + (size_t)(m_base + l15) * 256 + kq;
        const float* arow1 = arow0 + 16 * 256;
        const float* brow[3];
        const float* bias[3];
#pragma unroll
        for (int ni = 0; ni < 3; ++ni) {
            int col = n_base + ni * 16 + l15;
            int w = col >> 8, c = col & 255;
            const float* W = (w == 0) ? Wq : (w == 1) ? Wk : Wv;
            brow[ni] = W + (size_t)c * 256 + kq;
            bias[ni] = ((w == 0) ? bq : (w == 1) ? bk : bv) + c;
        }

#pragma unroll
        for (int ks = 0; ks < 8; ++ks) {
            int ko = ks * 32;
            bf16x8 a0 = cvt8(arow0 + ko);
            bf16x8 a1 = cvt8(arow1 + ko);
#pragma unroll
            for (int ni = 0; ni < 3; ++ni) {
                bf16x8 b = cvt8(brow[ni] + ko);
                acc[0][ni] = __builtin_amdgcn_mfma_f32_16x16x32_bf16(a0, b, acc[0][ni], 0, 0, 0);
                acc[1][ni] = __builtin_amdgcn_mfma_f32_16x16x32_bf16(a1, b, acc[1][ni], 0, 0, 0);
            }
        }

#pragma unroll
        for (int mi = 0; mi < 2; ++mi) {
#pragma unroll
            for (int ni = 0; ni < 3; ++ni) {
                int col = n_base + ni * 16 + l15;
                int w = col >> 8, c = col & 255;
                float bb = *bias[ni];
                float* outp = qkv + (size_t)w * ((size_t)NATOMS * FDIM) + c;
#pragma unroll
                for (int r = 0; r < 4; ++r) {
                    int row = m_base + mi * 16 + quad * 4 + r;
                    outp[(size_t)row * FDIM] = acc[mi][ni][r] + bb;
                }
            }
        }
    } else if (bid < 576) {
        // ----- A2T = (Wo2 @ Wo1)^T (fp32, 32x32 tile); j0==0 blocks: + c1 -----
        int t = bid - 512;
        int i0 = (t >> 3) * 32;
        int j0 = (t & 7) * 32;
        bool do_c1 = (t & 7) == 0;
        int tx = tid & 15;
        int ty = tid >> 4;
        int lm = tid >> 3;              // 0..31 (row in tile)
        int lk = (tid & 7) << 2;        // 0..28 (k offset)

        float acc[2][2] = {};
        float c1acc = 0.0f;

        for (int kt = 0; kt < 256; kt += 32) {
            const float4 av = *(const float4*)(Wo2 + (size_t)(i0 + lm) * 256 + kt + lk);
            const float4 bv = *(const float4*)(Wo1 + (size_t)(kt + lm) * 256 + j0 + lk);
            As[lk + 0][lm] = av.x; As[lk + 1][lm] = av.y;
            As[lk + 2][lm] = av.z; As[lk + 3][lm] = av.w;
            Bs[lm][lk + 0] = bv.x; Bs[lm][lk + 1] = bv.y;
            Bs[lm][lk + 2] = bv.z; Bs[lm][lk + 3] = bv.w;
            __syncthreads();

#pragma unroll
            for (int kk = 0; kk < 32; ++kk) {
                float a0 = As[kk][ty * 2], a1 = As[kk][ty * 2 + 1];
                float b0 = Bs[kk][tx * 2], b1 = Bs[kk][tx * 2 + 1];
                acc[0][0] = fmaf(a0, b0, acc[0][0]);
                acc[0][1] = fmaf(a0, b1, acc[0][1]);
                acc[1][0] = fmaf(a1, b0, acc[1][0]);
                acc[1][1] = fmaf(a1, b1, acc[1][1]);
            }
            if (do_c1) {
                float4 bb = *(const float4*)(bo1 + kt + lk);
                c1acc = fmaf(As[lk + 0][lm], bb.x, c1acc);
                c1acc = fmaf(As[lk + 1][lm], bb.y, c1acc);
                c1acc = fmaf(As[lk + 2][lm], bb.z, c1acc);
                c1acc = fmaf(As[lk + 3][lm], bb.w, c1acc);
            }
            __syncthreads();
        }

        // store transposed: A2T[k][n] = A2[n][k], n = i0+.., k = j0+..
#pragma unroll
        for (int i = 0; i < 2; ++i)
#pragma unroll
            for (int j = 0; j < 2; ++j)
                A2T[(size_t)(j0 + tx * 2 + j) * 256 + (i0 + ty * 2 + i)] = acc[i][j];

        if (do_c1) {
            c1acc += __shfl_xor(c1acc, 1, 8);
            c1acc += __shfl_xor(c1acc, 2, 8);
            c1acc += __shfl_xor(c1acc, 4, 8);
            if ((tid & 7) == 0) c1[i0 + lm] = c1acc;
        }
    } else {
        // -------- offsets + counts via LDS-staged seg; zero gcnt --------
        for (int i = tid; i < NATOMS; i += 256) segs[i] = seg[i];
        if (tid < NGRP) gcnt[tid] = 0;
        __syncthreads();
        if (tid < NGRP) {
            int g = tid;
            auto lb = [&](int val) {
                int lo = 0, hi = NATOMS;
                while (lo < hi) {
                    int mid = (lo + hi) >> 1;
                    if (segs[mid] < val) lo = mid + 1; else hi = mid;
                }
                return lo;
            };
            int a = lb(g);
            int b = lb(g + 1);
            off[g] = a;
            if (g == NGRP - 1) off[NGRP] = NATOMS;
            cntf[g] = (float)(b - a);
        }
    }
}

// ---------------------------------------------------------------------------
// K2: block-diagonal attention fused with per-group row-sum, PLUS the tail
// GEMM done by the last-arriving block of each group (no polling anywhere):
//   Ysum[g, h*32+d] = sum_j (sum_i silu(q_i.k_j)) * v_j[d]
//   out[g, :] = silu(Ysum[g] @ A2T + cnt_g*c1 + bo2)   (8th arriver only)
// Grid (128, 8).
// ---------------------------------------------------------------------------
__global__ __launch_bounds__(256) void attn_tail(
    const float* __restrict__ qkv, const int* __restrict__ off,
    float* __restrict__ Ysum, const float* __restrict__ A2T,
    const float* __restrict__ c1, const float* __restrict__ bo2,
    const float* __restrict__ cntf, int* __restrict__ gcnt,
    float* __restrict__ out)
{
    int g = blockIdx.x, h = blockIdx.y;
    int base = off[g];
    int end  = off[g + 1];
    base = min(max(base, 0), NATOMS);   // poison-safe clamps
    end  = min(max(end, base), NATOMS);
    int n = end - base;

    __shared__ float4 qt4[64 * 8];
    __shared__ float4 vt4[32 * 8];
    __shared__ float  wred[8][32];
    __shared__ float  w[32];
    __shared__ float  red[8][32];
    __shared__ int    lastf;

    int tid = threadIdx.x;
    int jj = tid & 31;
    int iq = tid >> 5;
    int d = tid & 31;
    int r = tid >> 5;

    const float* q = qkv;
    const float* k = qkv + (size_t)NATOMS * FDIM;
    const float* v = qkv + 2 * (size_t)NATOMS * FDIM;

    const float4* q4 = (const float4*)(q + (size_t)base * FDIM) + h * 8;
    const float4* k4 = (const float4*)(k + (size_t)base * FDIM) + h * 8;
    const float4* v4 = (const float4*)(v + (size_t)base * FDIM) + h * 8;

    float accY = 0.0f;

    for (int j0 = 0; j0 < n; j0 += 32) {
        int jt_n = min(32, n - j0);
        __syncthreads();
        for (int idx = tid; idx < jt_n * 8; idx += 256)
            vt4[idx] = v4[(size_t)(j0 + (idx >> 3)) * 64 + (idx & 7)];

        float4 kr[8];
        {
            int jrow = (jj < jt_n) ? (j0 + jj) : j0;
#pragma unroll
            for (int c = 0; c < 8; ++c) kr[c] = k4[(size_t)jrow * 64 + c];
        }

        float wpart = 0.0f;
        for (int i0 = 0; i0 < n; i0 += 64) {
            int it_n = min(64, n - i0);
            __syncthreads();
            for (int idx = tid; idx < it_n * 8; idx += 256)
                qt4[idx] = q4[(size_t)(i0 + (idx >> 3)) * 64 + (idx & 7)];
            __syncthreads();
            if (jj < jt_n) {
                for (int ii = iq; ii < it_n; ii += 8) {
                    const float4* qr = &qt4[ii * 8];
                    float s = 0.0f;
#pragma unroll
                    for (int c = 0; c < 8; ++c) {
                        float4 a = qr[c];
                        s = fmaf(a.x, kr[c].x, s);
                        s = fmaf(a.y, kr[c].y, s);
                        s = fmaf(a.z, kr[c].z, s);
                        s = fmaf(a.w, kr[c].w, s);
                    }
                    wpart += silu_f(s);
                }
            }
        }
        wred[iq][jj] = wpart;
        __syncthreads();
        if (tid < 32) {
            float s = 0.0f;
#pragma unroll
            for (int rr = 0; rr < 8; ++rr) s += wred[rr][tid];
            w[tid] = s;
        }
        __syncthreads();
        const float* vts = (const float*)vt4;
        for (int j = r; j < jt_n; j += 8)
            accY = fmaf(w[j], vts[j * 32 + d], accY);
    }

    red[r][d] = accY;
    __syncthreads();
    if (r == 0) {
        float s = 0.0f;
#pragma unroll
        for (int rr = 0; rr < 8; ++rr) s += red[rr][d];
        Ysum[(size_t)g * FDIM + h * DHEAD + d] = s;
    }

    // ---- last-arriver tail: 8th block of group g computes out[g,:] ----
    __threadfence();            // make Ysum slice visible at agent scope
    __syncthreads();
    if (tid == 0) {
        int prev = __hip_atomic_fetch_add(&gcnt[g], 1, __ATOMIC_ACQ_REL,
                                          __HIP_MEMORY_SCOPE_AGENT);
        lastf = (prev == NHEAD - 1) ? 1 : 0;
    }
    __syncthreads();
    if (!lastf) return;

    // stage the full Ysum row (agent-scope loads: fresh past local caches)
    float* ys = (float*)qt4;    // attn LDS no longer in use
    ys[tid] = __hip_atomic_load(&Ysum[(size_t)g * FDIM + tid],
                                __ATOMIC_RELAXED, __HIP_MEMORY_SCOPE_AGENT);
    __syncthreads();

    float s = 0.0f;
    for (int k0 = 0; k0 < 256; k0 += 8) {
#pragma unroll
        for (int kk = 0; kk < 8; ++kk)
            s = fmaf(ys[k0 + kk], A2T[(size_t)(k0 + kk) * 256 + tid], s);
    }
    out[(size_t)g * FDIM + tid] = silu_f(s + cntf[g] * c1[tid] + bo2[tid]);
}

// ---------------------------------------------------------------------------
extern "C" void kernel_launch(void* const* d_in, const int* in_sizes, int n_in,
                              void* d_out, int out_size, void* d_ws, size_t ws_size,
                              hipStream_t stream) {
    const float* x    = (const float*)d_in[0];
    const int*   eidx = (const int*)  d_in[1];
    const float* Wq   = (const float*)d_in[2];
    const float* bq   = (const float*)d_in[3];
    const float* Wk   = (const float*)d_in[4];
    const float* bk   = (const float*)d_in[5];
    const float* Wv   = (const float*)d_in[6];
    const float* bv   = (const float*)d_in[7];
    const float* Wo1  = (const float*)d_in[8];
    const float* bo1  = (const float*)d_in[9];
    const float* Wo2  = (const float*)d_in[10];
    const float* bo2  = (const float*)d_in[11];
    float* out = (float*)d_out;

    const int* seg = eidx + NATOMS;

    const size_t NF = (size_t)NATOMS * FDIM;   // 1,048,576
    const size_t GF = (size_t)NGRP * FDIM;     // 32,768

    float* qkv  = (float*)d_ws;                // q|k|v contiguous, 3*NF
    float* Ysum = qkv + 3 * NF;                // GF
    float* A2T  = Ysum + GF;                   // 256*256 (transposed)
    float* c1   = A2T + 256 * 256;             // 256
    float* cntf = c1 + 256;                    // 128
    int*   off  = (int*)(cntf + NGRP);         // 160 ints (129 used)
    int*   gcnt = off + 160;                   // 128 ints

    k1_qkv_a2<<<577, 256, 0, stream>>>(x, seg, Wq, Wk, Wv, bq, bk, bv,
                                       Wo1, bo1, Wo2, qkv, A2T, c1, cntf, off, gcnt);

    dim3 gattn(NGRP, NHEAD);
    attn_tail<<<gattn, 256, 0, stream>>>(qkv, off, Ysum, A2T, c1, bo2,
                                         cntf, gcnt, out);
}